// Round 3
// baseline (1604.376 us; speedup 1.0000x reference)
//
#include <hip/hip_runtime.h>
#include <hip/hip_bf16.h>
#include <cstdint>

// ---------------------------------------------------------------------------
// MANSF forward. Shapes: S=500 D=5 T=30 FT=512 H=64 E=20000 NREL=5 HEADS=8 NC=2
// Pipeline:
//  zero/count/scan/scatter : CSR of edges by dst           (independent)
//  gemm_gi   : GI[s,dt,192] = text[s]@tg_Wih^T + tg_bih    (the big GEMM)
//  gru5_attn<3>  : price GRU + attention -> xp[s,64]
//  text_gru_attn : 30-step GRU over GI (5 days batched) + attention -> news[s,5,64]
//  gru5_attn<64> : gt GRU over news + attention -> tv[s,64]
//  bilinear_ft   : ft[s,k]=tanh(tv·blW[k]·xp + blb), out1=tanh(ft@lxW+lxb)
//  xr1 / parts1 / rgat1 : relation-GAT layer 1 -> msg1[s,512]
//  xr2 / rgat2_final    : GAT layer 2 + elu + +out1 + softmax -> out[s,2]
// ws layout (floats): GI[0..14.4M) fullt[14.4M..19.2M) xp/news/tv/ft/out1,
//   CSR ints @19,457,024; GAT-phase buffers reuse the (dead) GI region.
// Requires ws_size >= ~78 MB.
// (Round 3: resubmitted unchanged — broker timeouts, no baseline yet.)
// ---------------------------------------------------------------------------

#define S_ 500
#define EDG 20000

__device__ __forceinline__ float lanebc(float v, int i) {
  return __int_as_float(__builtin_amdgcn_readlane(__float_as_int(v), i));
}
__device__ __forceinline__ float sigm(float x) { return 1.f / (1.f + expf(-x)); }
__device__ __forceinline__ float leaky(float x) { return x > 0.f ? x : 0.2f * x; }
__device__ __forceinline__ unsigned encf(float f) {
  unsigned u = __float_as_uint(f);
  return (u & 0x80000000u) ? ~u : (u | 0x80000000u);
}
__device__ __forceinline__ float decf(unsigned u) {
  unsigned v = (u & 0x80000000u) ? (u & 0x7fffffffu) : ~u;
  return __uint_as_float(v);
}

// ---------------- CSR build ----------------
__global__ void k_zero_ints(int* a, int n) {
  int i = blockIdx.x * 256 + threadIdx.x;
  if (i < n) a[i] = 0;
}
__global__ void k_count(const int* __restrict__ ei, int* counts) {
  int e = blockIdx.x * 256 + threadIdx.x;
  if (e < EDG) atomicAdd(&counts[ei[EDG + e]], 1);
}
__global__ void k_scan(const int* __restrict__ counts, int* rowptr) {
  __shared__ int tmp[512];
  int tid = threadIdx.x;
  tmp[tid] = (tid < S_) ? counts[tid] : 0;
  __syncthreads();
  for (int off = 1; off < 512; off <<= 1) {
    int t = (tid >= off) ? tmp[tid - off] : 0;
    __syncthreads();
    tmp[tid] += t;
    __syncthreads();
  }
  if (tid == 0) rowptr[0] = 0;
  if (tid < S_) rowptr[tid + 1] = tmp[tid];
}
__global__ void k_scatter(const int* __restrict__ ei, const int* __restrict__ rowptr,
                          int* fill, int* perm) {
  int e = blockIdx.x * 256 + threadIdx.x;
  if (e < EDG) {
    int d = ei[EDG + e];
    int pos = rowptr[d] + atomicAdd(&fill[d], 1);
    perm[pos] = e;
  }
}

// ---------------- big GEMM: GI = text @ tg_Wih^T + bih ----------------
// per stock: A[150,512] (M padded to 160) x B[192,512]^T -> C[150,192]
// M tiling: two full 64-row tiles (4 rows/thread) + one 32-row half tile
// (2 rows/thread, uniform across all waves so no SIMD imbalance).
// Per-thread FMAs/k = 48+48+24 = 120 (vs 144 for the 192-row padding).
__global__ __launch_bounds__(256, 2) void gemm_gi(const float* __restrict__ text,
                                                  const float* __restrict__ Wih,
                                                  const float* __restrict__ bih,
                                                  float* __restrict__ GI) {
  int s = blockIdx.x, tid = threadIdx.x;
  int tx = tid & 15, ty = tid >> 4;
  __shared__ float AsT[3 * 32 * 68];  // [tile][k][m-row], pad 68 (tile2 uses rows 0..31)
  __shared__ float BsT[32 * 196];     // [k][n-row], pad 196
  const float* A = text + (size_t)s * 150 * 512;
  const float* B = Wih + (size_t)s * 192 * 512;
  float acc[2][4][12];  // full tiles: rows mt*64 + ty*4 + i
  float acch[2][12];    // half tile: rows 128 + ty*2 + i
#pragma unroll
  for (int mt = 0; mt < 2; mt++)
#pragma unroll
    for (int i = 0; i < 4; i++)
#pragma unroll
      for (int jj = 0; jj < 12; jj++) acc[mt][i][jj] = 0.f;
#pragma unroll
  for (int i = 0; i < 2; i++)
#pragma unroll
    for (int jj = 0; jj < 12; jj++) acch[i][jj] = 0.f;

  for (int kc = 0; kc < 512; kc += 32) {
    __syncthreads();
    for (int idx = tid; idx < 5120; idx += 256) {  // rows 0..159
      int row = idx >> 5, col = idx & 31;
      float v = (row < 150) ? A[(size_t)row * 512 + kc + col] : 0.f;
      AsT[((row >> 6) * 32 + col) * 68 + (row & 63)] = v;
    }
    for (int idx = tid; idx < 6144; idx += 256) {
      int row = idx >> 5, col = idx & 31;
      BsT[col * 196 + row] = B[(size_t)row * 512 + kc + col];
    }
    __syncthreads();
#pragma unroll 8
    for (int k = 0; k < 32; k++) {
      float4 b0 = *(const float4*)&BsT[k * 196 + tx * 12];
      float4 b1v = *(const float4*)&BsT[k * 196 + tx * 12 + 4];
      float4 b2v = *(const float4*)&BsT[k * 196 + tx * 12 + 8];
      float bv[12] = {b0.x, b0.y, b0.z, b0.w, b1v.x, b1v.y,
                      b1v.z, b1v.w, b2v.x, b2v.y, b2v.z, b2v.w};
#pragma unroll
      for (int mt = 0; mt < 2; mt++) {
        float4 a4 = *(const float4*)&AsT[(mt * 32 + k) * 68 + ty * 4];
        float av[4] = {a4.x, a4.y, a4.z, a4.w};
#pragma unroll
        for (int i = 0; i < 4; i++)
#pragma unroll
          for (int jj = 0; jj < 12; jj++)
            acc[mt][i][jj] = fmaf(av[i], bv[jj], acc[mt][i][jj]);
      }
      {  // half tile: rows 128 + ty*2 + {0,1}, uniform work for every thread
        float2 a2 = *(const float2*)&AsT[(2 * 32 + k) * 68 + ty * 2];
        float ah[2] = {a2.x, a2.y};
#pragma unroll
        for (int i = 0; i < 2; i++)
#pragma unroll
          for (int jj = 0; jj < 12; jj++)
            acch[i][jj] = fmaf(ah[i], bv[jj], acch[i][jj]);
      }
    }
  }
#pragma unroll
  for (int mt = 0; mt < 2; mt++)
#pragma unroll
    for (int i = 0; i < 4; i++) {
      int row = mt * 64 + ty * 4 + i;  // 0..127, always valid
#pragma unroll
      for (int jj = 0; jj < 12; jj++) {
        int gc = tx * 12 + jj;
        GI[((size_t)s * 150 + row) * 192 + gc] = acc[mt][i][jj] + bih[s * 192 + gc];
      }
    }
#pragma unroll
  for (int i = 0; i < 2; i++) {
    int row = 128 + ty * 2 + i;
    if (row < 150) {
#pragma unroll
      for (int jj = 0; jj < 12; jj++) {
        int gc = tx * 12 + jj;
        GI[((size_t)s * 150 + row) * 192 + gc] = acch[i][jj] + bih[s * 192 + gc];
      }
    }
  }
}

// ---------------- generic 5-step GRU + additive attention ----------------
// block = 192 threads (3 waves). thread g owns gate-row g; h replicated per wave
// (lane j of every wave holds h[j]); cross-lane h via v_readlane.
template <int IN>
__global__ __launch_bounds__(192) void gru5_attn(
    const float* __restrict__ X, const float* __restrict__ Wih,
    const float* __restrict__ Whh, const float* __restrict__ bih,
    const float* __restrict__ bhh, const float* __restrict__ W1,
    const float* __restrict__ b1, const float* __restrict__ W2,
    const float* __restrict__ b2, const float* __restrict__ V,
    float* __restrict__ outv) {
  int s = blockIdx.x, tid = threadIdx.x, j = tid & 63, w = tid >> 6, g = tid;
  float wih[IN];
  {
    const float* p = Wih + ((size_t)s * 192 + g) * IN;
#pragma unroll
    for (int i = 0; i < IN; i++) wih[i] = p[i];
  }
  float whh[64];
  {
    const float* p = Whh + ((size_t)s * 192 + g) * 64;
#pragma unroll
    for (int i = 0; i < 64; i++) whh[i] = p[i];
  }
  float bi = bih[s * 192 + g], bh = bhh[s * 192 + g];
  __shared__ float gi_s[192], gh_s[192], full_s[5][64];
  float h = 0.f;
  for (int t = 0; t < 5; t++) {
    float gi = bi, gh = bh;
    if (IN == 3) {
      float x0 = X[((size_t)s * 5 + t) * 3 + 0];
      float x1 = X[((size_t)s * 5 + t) * 3 + 1];
      float x2 = X[((size_t)s * 5 + t) * 3 + 2];
      gi = fmaf(wih[0], x0, fmaf(wih[1], x1, fmaf(wih[2], x2, gi)));
    } else {
      float xl = X[((size_t)s * 5 + t) * IN + j];
#pragma unroll
      for (int i = 0; i < IN; i++) gi = fmaf(wih[i], lanebc(xl, i), gi);
    }
#pragma unroll
    for (int i = 0; i < 64; i++) gh = fmaf(whh[i], lanebc(h, i), gh);
    gi_s[g] = gi;
    gh_s[g] = gh;
    __syncthreads();
    float r = sigm(gi_s[j] + gh_s[j]);
    float z = sigm(gi_s[64 + j] + gh_s[64 + j]);
    float nn = tanhf(gi_s[128 + j] + r * gh_s[128 + j]);
    h = (1.f - z) * nn + z * h;
    if (w == 0) full_s[t][j] = h;
    __syncthreads();
  }
  if (w != 0) return;
  // attention (wave 0): u = last@W1 + b1 + b2
  float u = b1[s * 64 + j] + b2[s * 64 + j];
#pragma unroll
  for (int i = 0; i < 64; i++)
    u = fmaf(lanebc(h, i), W1[((size_t)s * 64 + i) * 64 + j], u);
  float vj = V[s * 64 + j];
  float sc[5];
#pragma unroll
  for (int t = 0; t < 5; t++) {
    float sv = u;
#pragma unroll
    for (int i = 0; i < 64; i++)
      sv = fmaf(full_s[t][i], W2[((size_t)s * 64 + i) * 64 + j], sv);
    sv = tanhf(sv) * vj;
#pragma unroll
    for (int m = 1; m < 64; m <<= 1) sv += __shfl_xor(sv, m, 64);
    sc[t] = sv;
  }
  float mx = sc[0];
#pragma unroll
  for (int t = 1; t < 5; t++) mx = fmaxf(mx, sc[t]);
  float den = 0.f, e[5];
#pragma unroll
  for (int t = 0; t < 5; t++) {
    e[t] = expf(sc[t] - mx);
    den += e[t];
  }
  float o = 0.f;
#pragma unroll
  for (int t = 0; t < 5; t++) o = fmaf(e[t] / den, full_s[t][j], o);
  outv[s * 64 + j] = o;
}

// ---------------- text GRU (30 steps, 5 days batched) + attention ----------
__global__ __launch_bounds__(192) void text_gru_attn(
    const float* __restrict__ GI, const float* __restrict__ Whh,
    const float* __restrict__ bhh, const float* __restrict__ W1,
    const float* __restrict__ b1, const float* __restrict__ W2,
    const float* __restrict__ b2, const float* __restrict__ V,
    float* __restrict__ fullt, float* __restrict__ news) {
  int s = blockIdx.x, tid = threadIdx.x, j = tid & 63, w = tid >> 6, g = tid;
  float whh[64];
  {
    const float* p = Whh + ((size_t)s * 192 + g) * 64;
#pragma unroll
    for (int i = 0; i < 64; i++) whh[i] = p[i];
  }
  float bh = bhh[s * 192 + g];
  __shared__ float gh_s[5 * 192];
  __shared__ float sc_s[3][30];
  const float* gib = GI + (size_t)s * 150 * 192;
  float h[5] = {0.f, 0.f, 0.f, 0.f, 0.f};
  for (int t = 0; t < 30; t++) {
    float gi0[5], gi1[5], gi2[5];
#pragma unroll
    for (int d = 0; d < 5; d++) {
      const float* p = gib + (d * 30 + t) * 192;
      gi0[d] = p[j];
      gi1[d] = p[64 + j];
      gi2[d] = p[128 + j];
    }
    float acc[5] = {bh, bh, bh, bh, bh};
#pragma unroll
    for (int i = 0; i < 64; i++) {
      float wv = whh[i];
#pragma unroll
      for (int d = 0; d < 5; d++) acc[d] = fmaf(wv, lanebc(h[d], i), acc[d]);
    }
#pragma unroll
    for (int d = 0; d < 5; d++) gh_s[d * 192 + g] = acc[d];
    __syncthreads();
#pragma unroll
    for (int d = 0; d < 5; d++) {
      float r = sigm(gi0[d] + gh_s[d * 192 + j]);
      float z = sigm(gi1[d] + gh_s[d * 192 + 64 + j]);
      float nn = tanhf(gi2[d] + r * gh_s[d * 192 + 128 + j]);
      h[d] = (1.f - z) * nn + z * h[d];
      if (w == 0) fullt[(((size_t)s * 5 + d) * 30 + t) * 64 + j] = h[d];
    }
    __syncthreads();
  }
  // attention per day; waves round-robin days (static unroll keeps h[] in regs)
  float vj = V[s * 64 + j];
  float bb = b1[s * 64 + j] + b2[s * 64 + j];
#pragma unroll
  for (int DD = 0; DD < 5; DD++) {
    if ((DD % 3) == w) {
      float u = bb;
#pragma unroll
      for (int i = 0; i < 64; i++)
        u = fmaf(lanebc(h[DD], i), W1[((size_t)s * 64 + i) * 64 + j], u);
      const float* fb = fullt + (((size_t)s * 5 + DD) * 30) * 64;
      for (int t = 0; t < 30; t++) {
        float fl = fb[t * 64 + j];
        float sv = u;
#pragma unroll
        for (int i = 0; i < 64; i++)
          sv = fmaf(lanebc(fl, i), W2[((size_t)s * 64 + i) * 64 + j], sv);
        sv = tanhf(sv) * vj;
#pragma unroll
        for (int m = 1; m < 64; m <<= 1) sv += __shfl_xor(sv, m, 64);
        if (j == 0) sc_s[w][t] = sv;
      }
      float mx = -3.4e38f;
      for (int t = 0; t < 30; t++) mx = fmaxf(mx, sc_s[w][t]);
      float den = 0.f;
      for (int t = 0; t < 30; t++) den += expf(sc_s[w][t] - mx);
      float o = 0.f;
      for (int t = 0; t < 30; t++) o = fmaf(expf(sc_s[w][t] - mx), fb[t * 64 + j], o);
      news[((size_t)s * 5 + DD) * 64 + j] = o / den;
    }
  }
}

// ---------------- bilinear + lx linear ----------------
__global__ __launch_bounds__(512) void bilinear_ft(
    const float* __restrict__ tv, const float* __restrict__ xp,
    const float* __restrict__ blW, const float* __restrict__ blb,
    const float* __restrict__ lxW, const float* __restrict__ lxb,
    float* __restrict__ ft, float* __restrict__ out1) {
  int s = blockIdx.x, tid = threadIdx.x;
  __shared__ float outer[4096];
  __shared__ float ft_s[64];
  for (int idx = tid; idx < 4096; idx += 512)
    outer[idx] = tv[s * 64 + (idx >> 6)] * xp[s * 64 + (idx & 63)];
  __syncthreads();
  int w = tid >> 6, l = tid & 63;
  for (int kk = w; kk < 64; kk += 8) {
    const float4* wp = (const float4*)(blW + ((size_t)s * 64 + kk) * 4096);
    float acc = 0.f;
#pragma unroll
    for (int it = 0; it < 16; it++) {
      float4 wv = wp[it * 64 + l];
      float4 ov = *(const float4*)&outer[it * 256 + l * 4];
      acc += wv.x * ov.x + wv.y * ov.y + wv.z * ov.z + wv.w * ov.w;
    }
#pragma unroll
    for (int m = 1; m < 64; m <<= 1) acc += __shfl_xor(acc, m, 64);
    if (l == 0) {
      float v = tanhf(acc + blb[s * 64 + kk]);
      ft[s * 64 + kk] = v;
      ft_s[kk] = v;
    }
  }
  __syncthreads();
  if (tid < 2) {
    float a = lxb[tid];
    for (int i = 0; i < 64; i++) a = fmaf(ft_s[i], lxW[i * 2 + tid], a);
    out1[s * 2 + tid] = tanhf(a);
  }
}

// ---------------- GAT layer 1 ----------------
__global__ __launch_bounds__(256) void xr1_kernel(const float* __restrict__ ft,
                                                  const float* __restrict__ g1W,
                                                  float* __restrict__ xr1) {
  int s = blockIdx.x, tid = threadIdx.x;
  __shared__ float fs[64];
  if (tid < 64) fs[tid] = ft[s * 64 + tid];
  __syncthreads();
  for (int idx = tid; idx < 2560; idx += 256) {
    int r = idx >> 9, o = idx & 511;
    float acc = 0.f;
    const float* wb = g1W + (size_t)r * 64 * 512 + o;
#pragma unroll 8
    for (int i = 0; i < 64; i++) acc = fmaf(fs[i], wb[i * 512], acc);
    xr1[((size_t)s * 5 + r) * 512 + o] = acc;
  }
}

__global__ void parts1_kernel(const float* __restrict__ xr1,
                              const float* __restrict__ g1a,
                              float* __restrict__ dp1, float* __restrict__ sp1) {
  int n = blockIdx.x, tid = threadIdx.x;
  if (tid < 40) {
    int t = tid >> 3, hh = tid & 7;
    const float* xb = xr1 + ((size_t)n * 5 + t) * 512 + hh * 64;
    const float* ab = g1a + (t * 8 + hh) * 128;
    float dp = 0.f, sp = 0.f;
    for (int d = 0; d < 64; d++) {
      float v = xb[d];
      dp = fmaf(ab[d], v, dp);
      sp = fmaf(ab[64 + d], v, sp);
    }
    dp1[n * 40 + tid] = dp;
    sp1[n * 40 + tid] = sp;
  }
}

__global__ __launch_bounds__(256) void rgat1_kernel(
    const int* __restrict__ ei, const int* __restrict__ et,
    const int* __restrict__ rowptr, const int* __restrict__ perm,
    const float* __restrict__ dp1, const float* __restrict__ sp1,
    const float* __restrict__ xr1, float* __restrict__ msg1) {
  int n = blockIdx.x, tid = threadIdx.x;
  __shared__ float dps[40];
  __shared__ unsigned mxu[8];
  __shared__ float fmx[8], den[8];
  if (tid < 40) dps[tid] = dp1[n * 40 + tid];
  if (tid < 8) mxu[tid] = 0u;
  __syncthreads();
  int start = rowptr[n], end = rowptr[n + 1];
  for (int idx = start + tid; idx < end; idx += 256) {
    int e = perm[idx];
    int t = et[e], sv = ei[e];
    const float* sp = sp1 + (sv * 5 + t) * 8;
#pragma unroll
    for (int hh = 0; hh < 8; hh++) {
      float sc = leaky(dps[t * 8 + hh] + sp[hh]);
      atomicMax(&mxu[hh], encf(sc));
    }
  }
  __syncthreads();
  if (tid < 8) fmx[tid] = decf(mxu[tid]);
  __syncthreads();
  int h0 = tid >> 6, h1 = h0 + 4;
  float m0 = fmx[h0], m1 = fmx[h1];
  float acc0 = 0.f, acc1 = 0.f, dl0 = 0.f, dl1 = 0.f;
  for (int idx = start; idx < end; idx++) {
    int e = perm[idx];
    int t = et[e], sv = ei[e];
    float p0 = expf(leaky(dps[t * 8 + h0] + sp1[(sv * 5 + t) * 8 + h0]) - m0);
    float p1 = expf(leaky(dps[t * 8 + h1] + sp1[(sv * 5 + t) * 8 + h1]) - m1);
    const float* xb = xr1 + ((size_t)sv * 5 + t) * 512;
    acc0 = fmaf(p0, xb[tid], acc0);
    acc1 = fmaf(p1, xb[tid + 256], acc1);
    if ((tid & 63) == 0) {
      dl0 += p0;
      dl1 += p1;
    }
  }
  if ((tid & 63) == 0) {
    den[h0] = dl0;
    den[h1] = dl1;
  }
  __syncthreads();
  msg1[(size_t)n * 512 + tid] = acc0 / (den[h0] + 1e-9f);
  msg1[(size_t)n * 512 + 256 + tid] = acc1 / (den[h1] + 1e-9f);
}

// ---------------- GAT layer 2 + final ----------------
__global__ void xr2_kernel(const float* __restrict__ msg1,
                           const float* __restrict__ g2W,
                           const float* __restrict__ g2a, float* __restrict__ xr2,
                           float* __restrict__ dp2, float* __restrict__ sp2) {
  int n = blockIdx.x, tid = threadIdx.x;
  __shared__ float ms[512];
  __shared__ float x2[10];
  for (int i = tid; i < 512; i += 64) ms[i] = msg1[(size_t)n * 512 + i];
  __syncthreads();
  if (tid < 10) {
    int r = tid >> 1, k = tid & 1;
    float acc = 0.f;
    for (int i = 0; i < 512; i++) acc = fmaf(ms[i], g2W[(r * 512 + i) * 2 + k], acc);
    xr2[n * 10 + tid] = acc;
    x2[tid] = acc;
  }
  __syncthreads();
  if (tid < 5) {
    dp2[n * 5 + tid] = g2a[tid * 4 + 0] * x2[tid * 2] + g2a[tid * 4 + 1] * x2[tid * 2 + 1];
    sp2[n * 5 + tid] = g2a[tid * 4 + 2] * x2[tid * 2] + g2a[tid * 4 + 3] * x2[tid * 2 + 1];
  }
}

__global__ void rgat2_final(const int* __restrict__ ei, const int* __restrict__ et,
                            const int* __restrict__ rowptr, const int* __restrict__ perm,
                            const float* __restrict__ dp2, const float* __restrict__ sp2,
                            const float* __restrict__ xr2, const float* __restrict__ out1,
                            float* __restrict__ out) {
  int n = blockIdx.x, tid = threadIdx.x;  // 64 threads
  int start = rowptr[n], end = rowptr[n + 1];
  float mloc = -3.4e38f;
  for (int idx = start + tid; idx < end; idx += 64) {
    int e = perm[idx];
    float sc = leaky(dp2[n * 5 + et[e]] + sp2[ei[e] * 5 + et[e]]);
    mloc = fmaxf(mloc, sc);
  }
#pragma unroll
  for (int m = 1; m < 64; m <<= 1) mloc = fmaxf(mloc, __shfl_xor(mloc, m, 64));
  float dl = 0.f, a0 = 0.f, a1 = 0.f;
  for (int idx = start + tid; idx < end; idx += 64) {
    int e = perm[idx];
    int t = et[e], sv = ei[e];
    float p = expf(leaky(dp2[n * 5 + t] + sp2[sv * 5 + t]) - mloc);
    dl += p;
    a0 = fmaf(p, xr2[(sv * 5 + t) * 2], a0);
    a1 = fmaf(p, xr2[(sv * 5 + t) * 2 + 1], a1);
  }
#pragma unroll
  for (int m = 1; m < 64; m <<= 1) {
    dl += __shfl_xor(dl, m, 64);
    a0 += __shfl_xor(a0, m, 64);
    a1 += __shfl_xor(a1, m, 64);
  }
  if (tid == 0) {
    float i0 = a0 / (dl + 1e-9f), i1 = a1 / (dl + 1e-9f);
    float e0 = (i0 > 0.f ? i0 : expm1f(i0)) + out1[n * 2];
    float e1 = (i1 > 0.f ? i1 : expm1f(i1)) + out1[n * 2 + 1];
    float mx = fmaxf(e0, e1);
    float z0 = expf(e0 - mx), z1 = expf(e1 - mx);
    out[n * 2] = z0 / (z0 + z1);
    out[n * 2 + 1] = z1 / (z0 + z1);
  }
}

// ---------------------------------------------------------------------------
extern "C" void kernel_launch(void* const* d_in, const int* in_sizes, int n_in,
                              void* d_out, int out_size, void* d_ws, size_t ws_size,
                              hipStream_t stream) {
  const float* text = (const float*)d_in[0];
  const float* price = (const float*)d_in[1];
  const int* ei = (const int*)d_in[2];
  const int* et = (const int*)d_in[3];
  const float* gpWih = (const float*)d_in[4];
  const float* gpWhh = (const float*)d_in[5];
  const float* gpbih = (const float*)d_in[6];
  const float* gpbhh = (const float*)d_in[7];
  const float* tgWih = (const float*)d_in[8];
  const float* tgWhh = (const float*)d_in[9];
  const float* tgbih = (const float*)d_in[10];
  const float* tgbhh = (const float*)d_in[11];
  const float* gtWih = (const float*)d_in[12];
  const float* gtWhh = (const float*)d_in[13];
  const float* gtbih = (const float*)d_in[14];
  const float* gtbhh = (const float*)d_in[15];
  const float* apW1 = (const float*)d_in[16];
  const float* apb1 = (const float*)d_in[17];
  const float* apW2 = (const float*)d_in[18];
  const float* apb2 = (const float*)d_in[19];
  const float* apV = (const float*)d_in[20];
  const float* atW1 = (const float*)d_in[22];
  const float* atb1 = (const float*)d_in[23];
  const float* atW2 = (const float*)d_in[24];
  const float* atb2 = (const float*)d_in[25];
  const float* atV = (const float*)d_in[26];
  const float* anW1 = (const float*)d_in[28];
  const float* anb1 = (const float*)d_in[29];
  const float* anW2 = (const float*)d_in[30];
  const float* anb2 = (const float*)d_in[31];
  const float* anV = (const float*)d_in[32];
  const float* blW = (const float*)d_in[34];
  const float* blb = (const float*)d_in[35];
  const float* lxW = (const float*)d_in[36];
  const float* lxb = (const float*)d_in[37];
  const float* g1W = (const float*)d_in[38];
  const float* g1a = (const float*)d_in[39];
  const float* g2W = (const float*)d_in[40];
  const float* g2a = (const float*)d_in[41];

  float* ws = (float*)d_ws;
  // phase-A buffers
  float* GI = ws + 0;              // 14,400,000
  float* fullt = ws + 14400000;    // 4,800,000
  float* xp = ws + 19200000;       // 32,000
  float* news = ws + 19232000;     // 160,000
  float* tv = ws + 19392000;       // 32,000
  float* ft = ws + 19424000;       // 32,000
  float* out1 = ws + 19456000;     // 1,000
  int* csr = (int*)(ws + 19457024);
  int* counts = csr;          // 500
  int* rowptr = csr + 512;    // 501
  int* fill = csr + 1024;     // 500
  int* perm = csr + 1536;     // 20,000
  // phase-B buffers reuse the GI region (dead after text_gru_attn)
  float* xr1 = ws + 0;           // 1,280,000
  float* dp1 = ws + 1280000;     // 20,000
  float* sp1 = ws + 1300000;     // 20,000
  float* msg1 = ws + 1320000;    // 256,000
  float* xr2 = ws + 1576000;     // 5,000
  float* dp2 = ws + 1581000;     // 2,500
  float* sp2 = ws + 1583500;     // 2,500

  float* outp = (float*)d_out;

  // CSR (independent of the heavy pipeline)
  hipLaunchKernelGGL(k_zero_ints, dim3(6), dim3(256), 0, stream, csr, 1536);
  hipLaunchKernelGGL(k_count, dim3((EDG + 255) / 256), dim3(256), 0, stream, ei, counts);
  hipLaunchKernelGGL(k_scan, dim3(1), dim3(512), 0, stream, counts, rowptr);
  hipLaunchKernelGGL(k_scatter, dim3((EDG + 255) / 256), dim3(256), 0, stream, ei, rowptr,
                     fill, perm);

  // main pipeline
  hipLaunchKernelGGL(gemm_gi, dim3(S_), dim3(256), 0, stream, text, tgWih, tgbih, GI);
  hipLaunchKernelGGL((gru5_attn<3>), dim3(S_), dim3(192), 0, stream, price, gpWih, gpWhh,
                     gpbih, gpbhh, apW1, apb1, apW2, apb2, apV, xp);
  hipLaunchKernelGGL(text_gru_attn, dim3(S_), dim3(192), 0, stream, GI, tgWhh, tgbhh, atW1,
                     atb1, atW2, atb2, atV, fullt, news);
  hipLaunchKernelGGL((gru5_attn<64>), dim3(S_), dim3(192), 0, stream, news, gtWih, gtWhh,
                     gtbih, gtbhh, anW1, anb1, anW2, anb2, anV, tv);
  hipLaunchKernelGGL(bilinear_ft, dim3(S_), dim3(512), 0, stream, tv, xp, blW, blb, lxW,
                     lxb, ft, out1);
  hipLaunchKernelGGL(xr1_kernel, dim3(S_), dim3(256), 0, stream, ft, g1W, xr1);
  hipLaunchKernelGGL(parts1_kernel, dim3(S_), dim3(64), 0, stream, xr1, g1a, dp1, sp1);
  hipLaunchKernelGGL(rgat1_kernel, dim3(S_), dim3(256), 0, stream, ei, et, rowptr, perm,
                     dp1, sp1, xr1, msg1);
  hipLaunchKernelGGL(xr2_kernel, dim3(S_), dim3(64), 0, stream, msg1, g2W, g2a, xr2, dp2,
                     sp2);
  hipLaunchKernelGGL(rgat2_final, dim3(S_), dim3(64), 0, stream, ei, et, rowptr, perm, dp2,
                     sp2, xr2, out1, outp);
}